// Round 1
// baseline (869.302 us; speedup 1.0000x reference)
//
#include <hip/hip_runtime.h>
#include <hip/hip_bf16.h>
#include <stdint.h>

#define M_DIM 4096
#define K_DIM 4096
#define N_DIM 12288
#define BM 128
#define BN 128
#define BK 64

typedef __attribute__((ext_vector_type(8))) short bf16x8;
typedef __attribute__((ext_vector_type(4))) float f32x4;

// fp32 -> bf16 by truncation (1 VALU op; bias ~2^-9 relative, fine vs 0.4 absmax)
static __device__ __forceinline__ short f2bf(float x) {
  union { float f; uint32_t u; } v; v.f = x;
  return (short)(v.u >> 16);
}

__global__ __launch_bounds__(256) void awq_gemm_kernel(
    const float* __restrict__ X, const int* __restrict__ Q,
    const float* __restrict__ S, const float* __restrict__ Bias,
    float* __restrict__ C) {
  // 128 rows x 8 chunks of bf16x8 (16 B) each = 16 KiB per tile.
  // Chunk index XOR-swizzled by (row & 7) so ds_read_b128 fragment reads
  // are 2-way max on banks (free), and staging writes stay conflict-free.
  __shared__ bf16x8 As[BM * 8];
  __shared__ bf16x8 Bs[BN * 8];

  const int tid  = threadIdx.x;
  const int lane = tid & 63;
  const int wave = tid >> 6;
  const int wm   = (wave >> 1) * 64;   // wave's M offset in tile
  const int wn   = (wave & 1) * 64;    // wave's N offset in tile
  const int m0   = blockIdx.y * BM;
  const int n0   = blockIdx.x * BN;

  const int rrow = lane & 15;          // A/B operand row (m or n) within 16
  const int quad = lane >> 4;          // k-quad: k = quad*8 + j

  f32x4 acc[4][4];
  #pragma unroll
  for (int i = 0; i < 4; ++i)
    #pragma unroll
    for (int j = 0; j < 4; ++j)
      acc[i][j] = (f32x4){0.f, 0.f, 0.f, 0.f};

  for (int k0 = 0; k0 < K_DIM; k0 += BK) {
    // ---- stage A: fp32 -> bf16, 128x64 tile, 4 chunks (32 floats) / thread ----
    #pragma unroll
    for (int r = 0; r < 4; ++r) {
      const int ch  = tid + 256 * r;       // 0..1023
      const int row = ch >> 3;             // 0..127
      const int c   = ch & 7;              // 16B chunk within row
      const float* p = X + (size_t)(m0 + row) * K_DIM + k0 + c * 8;
      f32x4 v0 = *(const f32x4*)p;
      f32x4 v1 = *(const f32x4*)(p + 4);
      bf16x8 w;
      w[0] = f2bf(v0.x); w[1] = f2bf(v0.y); w[2] = f2bf(v0.z); w[3] = f2bf(v0.w);
      w[4] = f2bf(v1.x); w[5] = f2bf(v1.y); w[6] = f2bf(v1.z); w[7] = f2bf(v1.w);
      As[row * 8 + (c ^ (row & 7))] = w;
    }
    // ---- stage B: one int32 = 8 nibbles = one 16B bf16 chunk ----
    // BK=64 divides GROUP_SIZE=128, so scale is a per-row scalar per K-tile.
    #pragma unroll
    for (int r = 0; r < 4; ++r) {
      const int idx = tid + 256 * r;       // 0..1023
      const int row = idx >> 3;            // n within tile, 0..127
      const int c   = idx & 7;             // which int32 within the K-slice
      const uint32_t q = (uint32_t)Q[(size_t)(n0 + row) * (K_DIM / 8) + (k0 >> 3) + c];
      const float sc = S[(size_t)(n0 + row) * (K_DIM / 128) + (k0 >> 7)];
      bf16x8 w;
      #pragma unroll
      for (int j = 0; j < 8; ++j) {
        // high nibble first: W[n, 8p+j] = ((q >> (28-4j)) & 15) * scale
        w[j] = f2bf((float)((q >> (28 - 4 * j)) & 15u) * sc);
      }
      Bs[row * 8 + (c ^ (row & 7))] = w;
    }
    __syncthreads();

    // ---- compute: 2 k-steps of 32, 4x4 MFMAs per wave ----
    #pragma unroll
    for (int kk = 0; kk < 2; ++kk) {
      const int kch = kk * 4 + quad;       // 16B chunk index for this k-quad
      bf16x8 a[4], b[4];
      #pragma unroll
      for (int mi = 0; mi < 4; ++mi) {
        const int row = wm + mi * 16 + rrow;
        a[mi] = As[row * 8 + (kch ^ (row & 7))];
      }
      #pragma unroll
      for (int ni = 0; ni < 4; ++ni) {
        const int row = wn + ni * 16 + rrow;
        b[ni] = Bs[row * 8 + (kch ^ (row & 7))];
      }
      #pragma unroll
      for (int mi = 0; mi < 4; ++mi)
        #pragma unroll
        for (int ni = 0; ni < 4; ++ni)
          acc[mi][ni] = __builtin_amdgcn_mfma_f32_16x16x32_bf16(
              a[mi], b[ni], acc[mi][ni], 0, 0, 0);
    }
    __syncthreads();
  }

  // ---- epilogue: C/D layout col(n)=lane&15, row(m)=quad*4+reg  [m89] ----
  #pragma unroll
  for (int ni = 0; ni < 4; ++ni) {
    const int n = n0 + wn + ni * 16 + rrow;
    const float bv = Bias[n];
    #pragma unroll
    for (int mi = 0; mi < 4; ++mi) {
      const int mbase = m0 + wm + mi * 16 + quad * 4;
      #pragma unroll
      for (int rr = 0; rr < 4; ++rr) {
        C[(size_t)(mbase + rr) * N_DIM + n] = acc[mi][ni][rr] + bv;
      }
    }
  }
}

extern "C" void kernel_launch(void* const* d_in, const int* in_sizes, int n_in,
                              void* d_out, int out_size, void* d_ws, size_t ws_size,
                              hipStream_t stream) {
  const float* X    = (const float*)d_in[0];
  const int*   Q    = (const int*)d_in[1];
  const float* S    = (const float*)d_in[2];
  const float* Bias = (const float*)d_in[3];
  float* C = (float*)d_out;
  dim3 grid(N_DIM / BN, M_DIM / BM);  // (96, 32)
  awq_gemm_kernel<<<grid, dim3(256), 0, stream>>>(X, Q, S, Bias, C);
}

// Round 3
// 798.947 us; speedup vs baseline: 1.0881x; 1.0881x over previous
//
#include <hip/hip_runtime.h>
#include <stdint.h>

#define M_DIM 4096
#define K_DIM 4096
#define N_DIM 12288
#define BM 128
#define BN 128
#define BK 64

typedef __attribute__((ext_vector_type(8))) _Float16 half8;
typedef __attribute__((ext_vector_type(2))) __fp16 fp16x2;
typedef __attribute__((ext_vector_type(4))) float f32x4;

#define GLOAD_LDS16(gp, lp)                                                   \
  __builtin_amdgcn_global_load_lds(                                           \
      (const __attribute__((address_space(1))) void*)(gp),                    \
      (__attribute__((address_space(3))) void*)(lp), 16, 0, 0)

// 8 nibbles (high-first) -> 8 f16 weights, single-rounded:
// h = 1024 + n exactly (0x6400|n); (h - 1024) is exact; one mul rounds.
static __device__ __forceinline__ half8 dequant8(uint32_t q, _Float16 sh) {
  union { uint32_t u[4]; half8 h; } w;
  w.u[0] = 0x64006400u | ((q >> 28) & 0xFu) | ((q >> 8)  & 0xF0000u);
  w.u[1] = 0x64006400u | ((q >> 20) & 0xFu) | ( q         & 0xF0000u);
  w.u[2] = 0x64006400u | ((q >> 12) & 0xFu) | ((q << 8)  & 0xF0000u);
  w.u[3] = 0x64006400u | ((q >> 4)  & 0xFu) | ((q << 16) & 0xF0000u);
  half8 hv = w.h;
  half8 mm, ss;
  #pragma unroll
  for (int i = 0; i < 8; ++i) { mm[i] = (_Float16)(-1024.0f); ss[i] = sh; }
  return (hv + mm) * ss;   // pk_add_f16 + pk_mul_f16, vectorized
}

__global__ __launch_bounds__(256) void cvt_f32_f16(const float* __restrict__ X,
                                                   _Float16* __restrict__ XH) {
  const size_t i = ((size_t)blockIdx.x * 256 + threadIdx.x) * 8;
  f32x4 v0 = *(const f32x4*)(X + i);
  f32x4 v1 = *(const f32x4*)(X + i + 4);
  union { fp16x2 h2[4]; half8 h8; } u;
  u.h2[0] = __builtin_amdgcn_cvt_pkrtz(v0.x, v0.y);
  u.h2[1] = __builtin_amdgcn_cvt_pkrtz(v0.z, v0.w);
  u.h2[2] = __builtin_amdgcn_cvt_pkrtz(v1.x, v1.y);
  u.h2[3] = __builtin_amdgcn_cvt_pkrtz(v1.z, v1.w);
  *(half8*)(XH + i) = u.h8;
}

template <bool PRE>
__global__ __launch_bounds__(256) void awq_gemm(
    const float* __restrict__ X, const _Float16* __restrict__ XH,
    const int* __restrict__ Q, const float* __restrict__ S,
    const float* __restrict__ Bias, float* __restrict__ C) {
  // 128 rows x 8 chunks of 16 B; chunk index XOR-swizzled by (row&7) so
  // fragment ds_read_b128 is 2-way max (free). For the PRE path the swizzle
  // is applied on the SOURCE address side (global_load_lds dest is lane-order).
  __shared__ half8 As[BM * 8];
  __shared__ half8 Bs[BN * 8];

  const int tid  = threadIdx.x;
  const int lane = tid & 63;
  const int wave = tid >> 6;
  const int wm   = (wave >> 1) * 64;
  const int wn   = (wave & 1) * 64;
  const int m0   = blockIdx.y * BM;
  const int n0   = blockIdx.x * BN;
  const int rrow = lane & 15;
  const int quad = lane >> 4;

  // Per-lane A source pointers (PRE path): lane l of wave w, call r stages
  // LDS slot s=(w*4+r)*64+l; that slot's (row, chunk) determines the global
  // chunk via the inverse swizzle c = (s&7) ^ (row&7).
  const _Float16* a_gp[4];
  if (PRE) {
    #pragma unroll
    for (int r = 0; r < 4; ++r) {
      const int slot = (wave * 4 + r) * 64 + lane;
      const int row  = slot >> 3;
      const int c    = (slot & 7) ^ (row & 7);
      a_gp[r] = XH + (size_t)(m0 + row) * K_DIM + c * 8;
    }
  }

  int brow[4], bcol[4];
  #pragma unroll
  for (int r = 0; r < 4; ++r) {
    const int idx = tid + 256 * r;
    brow[r] = idx >> 3;
    bcol[r] = idx & 7;
  }

  f32x4 acc[4][4];
  #pragma unroll
  for (int i = 0; i < 4; ++i)
    #pragma unroll
    for (int j = 0; j < 4; ++j)
      acc[i][j] = (f32x4){0.f, 0.f, 0.f, 0.f};

  for (int k0 = 0; k0 < K_DIM; k0 += BK) {
    // ---- stage A ----
    if (PRE) {
      #pragma unroll
      for (int r = 0; r < 4; ++r)
        GLOAD_LDS16(a_gp[r] + k0, &As[(wave * 4 + r) * 64]);
    } else {
      #pragma unroll
      for (int r = 0; r < 4; ++r) {
        const int ch  = tid + 256 * r;
        const int row = ch >> 3;
        const int c   = ch & 7;
        const float* p = X + (size_t)(m0 + row) * K_DIM + k0 + c * 8;
        f32x4 v0 = *(const f32x4*)p;
        f32x4 v1 = *(const f32x4*)(p + 4);
        union { fp16x2 h2[4]; half8 h8; } u;
        u.h2[0] = __builtin_amdgcn_cvt_pkrtz(v0.x, v0.y);
        u.h2[1] = __builtin_amdgcn_cvt_pkrtz(v0.z, v0.w);
        u.h2[2] = __builtin_amdgcn_cvt_pkrtz(v1.x, v1.y);
        u.h2[3] = __builtin_amdgcn_cvt_pkrtz(v1.z, v1.w);
        As[row * 8 + (c ^ (row & 7))] = u.h8;
      }
    }
    // ---- stage B: dequant, BK=64 divides GROUP=128 -> scalar scale/row ----
    #pragma unroll
    for (int r = 0; r < 4; ++r) {
      const int row = brow[r];
      const int c   = bcol[r];
      const uint32_t q =
          (uint32_t)Q[(size_t)(n0 + row) * (K_DIM / 8) + (k0 >> 3) + c];
      const float s = S[(size_t)(n0 + row) * (K_DIM / 128) + (k0 >> 7)];
      Bs[row * 8 + (c ^ (row & 7))] = dequant8(q, (_Float16)s);
    }
    __syncthreads();

    // ---- compute: 2 k-steps, 4x4 MFMAs/wave ----
    #pragma unroll
    for (int kk = 0; kk < 2; ++kk) {
      const int kch = kk * 4 + quad;
      half8 a[4], b[4];
      #pragma unroll
      for (int mi = 0; mi < 4; ++mi) {
        const int row = wm + mi * 16 + rrow;
        a[mi] = As[row * 8 + (kch ^ (row & 7))];
      }
      #pragma unroll
      for (int ni = 0; ni < 4; ++ni) {
        const int row = wn + ni * 16 + rrow;
        b[ni] = Bs[row * 8 + (kch ^ (row & 7))];
      }
      #pragma unroll
      for (int mi = 0; mi < 4; ++mi)
        #pragma unroll
        for (int ni = 0; ni < 4; ++ni)
          acc[mi][ni] = __builtin_amdgcn_mfma_f32_16x16x32_f16(
              a[mi], b[ni], acc[mi][ni], 0, 0, 0);
    }
    __syncthreads();
  }

  // ---- epilogue: C/D layout col(n)=lane&15, row(m)=quad*4+reg [m89] ----
  #pragma unroll
  for (int ni = 0; ni < 4; ++ni) {
    const int n = n0 + wn + ni * 16 + rrow;
    const float bv = Bias[n];
    #pragma unroll
    for (int mi = 0; mi < 4; ++mi) {
      const int mbase = m0 + wm + mi * 16 + quad * 4;
      #pragma unroll
      for (int rr = 0; rr < 4; ++rr) {
        C[(size_t)(mbase + rr) * N_DIM + n] = acc[mi][ni][rr] + bv;
      }
    }
  }
}

extern "C" void kernel_launch(void* const* d_in, const int* in_sizes, int n_in,
                              void* d_out, int out_size, void* d_ws, size_t ws_size,
                              hipStream_t stream) {
  const float* X    = (const float*)d_in[0];
  const int*   Q    = (const int*)d_in[1];
  const float* S    = (const float*)d_in[2];
  const float* Bias = (const float*)d_in[3];
  float* C = (float*)d_out;
  dim3 grid(N_DIM / BN, M_DIM / BM);  // (96, 32)
  const size_t need = (size_t)M_DIM * K_DIM * sizeof(_Float16);  // 32 MiB
  if (ws_size >= need) {
    _Float16* XH = (_Float16*)d_ws;
    cvt_f32_f16<<<(M_DIM * (size_t)K_DIM) / 8 / 256, 256, 0, stream>>>(X, XH);
    awq_gemm<true><<<grid, dim3(256), 0, stream>>>(X, XH, Q, S, Bias, C);
  } else {
    awq_gemm<false><<<grid, dim3(256), 0, stream>>>(X, nullptr, Q, S, Bias, C);
  }
}